// Round 1
// baseline (620.126 us; speedup 1.0000x reference)
//
#include <hip/hip_runtime.h>
#include <hip/hip_bf16.h>
#include <stdint.h>

#define BB 2
#define SS 2048
#define HH 1024
#define NHH 16
#define HDD 64
#define MM (BB*SS)   // 4096

typedef __attribute__((ext_vector_type(8))) short short8;
typedef __attribute__((ext_vector_type(4))) float f32x4;
typedef __attribute__((ext_vector_type(4))) unsigned short u16x4;

__device__ __forceinline__ unsigned short f2bf(float x){
  unsigned u = __float_as_uint(x);
  u += 0x7fffu + ((u >> 16) & 1u);   // RNE; inputs are finite
  return (unsigned short)(u >> 16);
}
__device__ __forceinline__ float bf2f(unsigned short h){
  return __uint_as_float(((unsigned)h) << 16);
}

// ---------------- conversion kernels ----------------
__global__ void k_split(const float* __restrict__ in, unsigned short* __restrict__ hi,
                        unsigned short* __restrict__ lo, int n4){
  int i = blockIdx.x * blockDim.x + threadIdx.x;
  if (i >= n4) return;
  f32x4 x = ((const f32x4*)in)[i];
  u16x4 h, l;
  #pragma unroll
  for (int j = 0; j < 4; ++j){
    unsigned short hb = f2bf(x[j]);
    h[j] = hb;
    l[j] = f2bf(x[j] - bf2f(hb));
  }
  ((u16x4*)hi)[i] = h;
  ((u16x4*)lo)[i] = l;
}

__global__ void k_addsplit(const float* __restrict__ a, const float* __restrict__ b,
                           unsigned short* __restrict__ hi, unsigned short* __restrict__ lo, int n4){
  int i = blockIdx.x * blockDim.x + threadIdx.x;
  if (i >= n4) return;
  f32x4 x = ((const f32x4*)a)[i] + ((const f32x4*)b)[i];
  u16x4 h, l;
  #pragma unroll
  for (int j = 0; j < 4; ++j){
    unsigned short hb = f2bf(x[j]);
    h[j] = hb;
    l[j] = f2bf(x[j] - bf2f(hb));
  }
  ((u16x4*)hi)[i] = h;
  ((u16x4*)lo)[i] = l;
}

__global__ void k_addplain(const float* __restrict__ a, const float* __restrict__ b,
                           unsigned short* __restrict__ w, int n4){
  int i = blockIdx.x * blockDim.x + threadIdx.x;
  if (i >= n4) return;
  f32x4 x = ((const f32x4*)a)[i] + ((const f32x4*)b)[i];
  u16x4 h;
  #pragma unroll
  for (int j = 0; j < 4; ++j) h[j] = f2bf(x[j]);
  ((u16x4*)w)[i] = h;
}

// ---------------- plain GEMM: C[M,N] = A[M,K] * B[N,K]^T ----------------
// EPI==1: bf16 output written transposed per-head as vT[(b*HH + n)*SS + s]
// EPI==2: fp32 output C[M,N]
template<int EPI>
__global__ __launch_bounds__(256, 2)
void gemm_bt(const unsigned short* __restrict__ A, const unsigned short* __restrict__ Bm,
             void* __restrict__ Cout, int M, int N, int K)
{
  __shared__ unsigned short As[128*32];
  __shared__ unsigned short Bs[128*32];
  const int tid = threadIdx.x;
  const int mb0 = blockIdx.y * 128, nb0 = blockIdx.x * 128;
  const int w  = tid >> 6, lane = tid & 63;
  const int wr = w >> 1,  wc = w & 1;
  const int lg = lane >> 4, lr = lane & 15;

  f32x4 zero4 = {0.f, 0.f, 0.f, 0.f};
  f32x4 acc[4][4];
  #pragma unroll
  for (int mi = 0; mi < 4; ++mi)
    #pragma unroll
    for (int ni = 0; ni < 4; ++ni) acc[mi][ni] = zero4;

  const unsigned short* Abase = A  + (size_t)mb0 * K;
  const unsigned short* Bbase = Bm + (size_t)nb0 * K;

  for (int kb = 0; kb < K; kb += 32) {
    __syncthreads();
    #pragma unroll
    for (int i = 0; i < 2; ++i){
      int c = i*256 + tid;
      int row = c >> 2, off = (c & 3) << 3;
      size_t go = (size_t)row * K + kb + off;
      __builtin_amdgcn_global_load_lds(
          (const __attribute__((address_space(1))) void*)(Abase + go),
          (__attribute__((address_space(3))) void*)(&As[c*8]), 16, 0, 0);
      __builtin_amdgcn_global_load_lds(
          (const __attribute__((address_space(1))) void*)(Bbase + go),
          (__attribute__((address_space(3))) void*)(&Bs[c*8]), 16, 0, 0);
    }
    __syncthreads();
    short8 af[4], bfr[4];
    #pragma unroll
    for (int mi = 0; mi < 4; ++mi) af[mi]  = *(const short8*)&As[(wr*64 + mi*16 + lr)*32 + lg*8];
    #pragma unroll
    for (int ni = 0; ni < 4; ++ni) bfr[ni] = *(const short8*)&Bs[(wc*64 + ni*16 + lr)*32 + lg*8];
    #pragma unroll
    for (int mi = 0; mi < 4; ++mi)
      #pragma unroll
      for (int ni = 0; ni < 4; ++ni)
        acc[mi][ni] = __builtin_amdgcn_mfma_f32_16x16x32_bf16(af[mi], bfr[ni], acc[mi][ni], 0, 0, 0);
  }

  #pragma unroll
  for (int mi = 0; mi < 4; ++mi){
    #pragma unroll
    for (int ni = 0; ni < 4; ++ni){
      int n  = nb0 + wc*64 + ni*16 + lr;
      int m0 = mb0 + wr*64 + mi*16 + 4*lg;
      if constexpr (EPI == 1) {
        unsigned short* vt = (unsigned short*)Cout;
        int b = m0 >> 11, s0 = m0 & 2047;
        u16x4 pk;
        #pragma unroll
        for (int r = 0; r < 4; ++r) pk[r] = f2bf(acc[mi][ni][r]);
        *(u16x4*)&vt[((size_t)(b*HH + n))*SS + s0] = pk;
      } else {
        float* C = (float*)Cout;
        #pragma unroll
        for (int r = 0; r < 4; ++r) C[(size_t)(m0 + r)*N + n] = acc[mi][ni][r];
      }
    }
  }
}

// ---------------- split GEMM (fp32-grade): C = (Ah+Al) * (Bh+Bl)^T, drop Al*Bl ----------------
__global__ __launch_bounds__(256, 2)
void gemm_bt_split(const unsigned short* __restrict__ Ah, const unsigned short* __restrict__ Al,
                   const unsigned short* __restrict__ Bh, const unsigned short* __restrict__ Bl,
                   unsigned short* __restrict__ Ch, unsigned short* __restrict__ Cl,
                   int M, int N, int K)
{
  __shared__ unsigned short Ash[128*32], Asl[128*32], Bsh[128*32], Bsl[128*32];
  const int tid = threadIdx.x;
  const int mb0 = blockIdx.y * 128, nb0 = blockIdx.x * 128;
  const int w  = tid >> 6, lane = tid & 63;
  const int wr = w >> 1,  wc = w & 1;
  const int lg = lane >> 4, lr = lane & 15;

  f32x4 zero4 = {0.f, 0.f, 0.f, 0.f};
  f32x4 acc[4][4];
  #pragma unroll
  for (int mi = 0; mi < 4; ++mi)
    #pragma unroll
    for (int ni = 0; ni < 4; ++ni) acc[mi][ni] = zero4;

  const unsigned short* Ahb = Ah + (size_t)mb0 * K;
  const unsigned short* Alb = Al + (size_t)mb0 * K;
  const unsigned short* Bhb = Bh + (size_t)nb0 * K;
  const unsigned short* Blb = Bl + (size_t)nb0 * K;

  for (int kb = 0; kb < K; kb += 32) {
    __syncthreads();
    #pragma unroll
    for (int i = 0; i < 2; ++i){
      int c = i*256 + tid;
      int row = c >> 2, off = (c & 3) << 3;
      size_t go = (size_t)row * K + kb + off;
      __builtin_amdgcn_global_load_lds(
          (const __attribute__((address_space(1))) void*)(Ahb + go),
          (__attribute__((address_space(3))) void*)(&Ash[c*8]), 16, 0, 0);
      __builtin_amdgcn_global_load_lds(
          (const __attribute__((address_space(1))) void*)(Alb + go),
          (__attribute__((address_space(3))) void*)(&Asl[c*8]), 16, 0, 0);
      __builtin_amdgcn_global_load_lds(
          (const __attribute__((address_space(1))) void*)(Bhb + go),
          (__attribute__((address_space(3))) void*)(&Bsh[c*8]), 16, 0, 0);
      __builtin_amdgcn_global_load_lds(
          (const __attribute__((address_space(1))) void*)(Blb + go),
          (__attribute__((address_space(3))) void*)(&Bsl[c*8]), 16, 0, 0);
    }
    __syncthreads();
    short8 ah4[4], al4[4], bh4[4], bl4[4];
    #pragma unroll
    for (int mi = 0; mi < 4; ++mi){
      int ro = (wr*64 + mi*16 + lr)*32 + lg*8;
      ah4[mi] = *(const short8*)&Ash[ro];
      al4[mi] = *(const short8*)&Asl[ro];
    }
    #pragma unroll
    for (int ni = 0; ni < 4; ++ni){
      int ro = (wc*64 + ni*16 + lr)*32 + lg*8;
      bh4[ni] = *(const short8*)&Bsh[ro];
      bl4[ni] = *(const short8*)&Bsl[ro];
    }
    #pragma unroll
    for (int mi = 0; mi < 4; ++mi)
      #pragma unroll
      for (int ni = 0; ni < 4; ++ni){
        acc[mi][ni] = __builtin_amdgcn_mfma_f32_16x16x32_bf16(ah4[mi], bh4[ni], acc[mi][ni], 0, 0, 0);
        acc[mi][ni] = __builtin_amdgcn_mfma_f32_16x16x32_bf16(al4[mi], bh4[ni], acc[mi][ni], 0, 0, 0);
        acc[mi][ni] = __builtin_amdgcn_mfma_f32_16x16x32_bf16(ah4[mi], bl4[ni], acc[mi][ni], 0, 0, 0);
      }
  }

  #pragma unroll
  for (int mi = 0; mi < 4; ++mi){
    #pragma unroll
    for (int ni = 0; ni < 4; ++ni){
      int n  = nb0 + wc*64 + ni*16 + lr;
      int m0 = mb0 + wr*64 + mi*16 + 4*lg;
      #pragma unroll
      for (int r = 0; r < 4; ++r){
        float x = acc[mi][ni][r];
        unsigned short hb = f2bf(x);
        unsigned short lb = f2bf(x - bf2f(hb));
        size_t o = (size_t)(m0 + r)*N + n;
        Ch[o] = hb;
        Cl[o] = lb;
      }
    }
  }
}

// ---------------- flash attention ----------------
// grid: B*NH*(S/64) blocks, 256 thr (4 waves x 16 q-rows). KVBLK=32.
// q,k given as split bf16 (hi,lo); scores = (qh+ql)(kh+kl)^T (3-term) in fp32.
__global__ __launch_bounds__(256, 2)
void attn_fwd(const unsigned short* __restrict__ qh, const unsigned short* __restrict__ ql,
              const unsigned short* __restrict__ kh, const unsigned short* __restrict__ kl,
              const unsigned short* __restrict__ vt, const float* __restrict__ mask,
              unsigned short* __restrict__ ao)
{
  __shared__ unsigned short P[4][16][40];   // per-wave P-tile, +8 pad vs bank conflicts
  const int tid = threadIdx.x;
  const int w = tid >> 6, lane = tid & 63;
  const int lg = lane >> 4, lr = lane & 15;
  const int bid = blockIdx.x;
  const int qb = bid & 31, h = (bid >> 5) & 15, b = bid >> 9;
  const int q0 = qb*64 + w*16;
  const int hoff = h*64;

  short8 qfh[2], qfl[2];
  {
    size_t qoff = ((size_t)(b*SS + q0 + lr))*HH + hoff + lg*8;
    qfh[0] = *(const short8*)(qh + qoff);
    qfl[0] = *(const short8*)(ql + qoff);
    qfh[1] = *(const short8*)(qh + qoff + 32);
    qfl[1] = *(const short8*)(ql + qoff + 32);
  }
  float m_run[4] = {-1e30f, -1e30f, -1e30f, -1e30f};
  float l_run[4] = {0.f, 0.f, 0.f, 0.f};
  f32x4 zero4 = {0.f, 0.f, 0.f, 0.f};
  f32x4 acc[4];
  #pragma unroll
  for (int d4 = 0; d4 < 4; ++d4) acc[d4] = zero4;
  const size_t mrow = ((size_t)(b*SS + q0 + 4*lg))*SS;

  for (int kv = 0; kv < SS; kv += 32) {
    f32x4 sc[2];
    #pragma unroll
    for (int nb = 0; nb < 2; ++nb){
      size_t krow = ((size_t)(b*SS + kv + nb*16 + lr))*HH + hoff + lg*8;
      short8 k0h = *(const short8*)(kh + krow);
      short8 k1h = *(const short8*)(kh + krow + 32);
      short8 k0l = *(const short8*)(kl + krow);
      short8 k1l = *(const short8*)(kl + krow + 32);
      f32x4 d = zero4;
      d = __builtin_amdgcn_mfma_f32_16x16x32_bf16(qfh[0], k0h, d, 0, 0, 0);
      d = __builtin_amdgcn_mfma_f32_16x16x32_bf16(qfh[1], k1h, d, 0, 0, 0);
      d = __builtin_amdgcn_mfma_f32_16x16x32_bf16(qfh[0], k0l, d, 0, 0, 0);
      d = __builtin_amdgcn_mfma_f32_16x16x32_bf16(qfh[1], k1l, d, 0, 0, 0);
      d = __builtin_amdgcn_mfma_f32_16x16x32_bf16(qfl[0], k0h, d, 0, 0, 0);
      d = __builtin_amdgcn_mfma_f32_16x16x32_bf16(qfl[1], k1h, d, 0, 0, 0);
      sc[nb] = d;
    }
    float s0[4], s1[4], rmax[4];
    #pragma unroll
    for (int r = 0; r < 4; ++r){
      float mk0 = mask[mrow + (size_t)r*SS + kv + lr];
      float mk1 = mask[mrow + (size_t)r*SS + kv + 16 + lr];
      s0[r] = fmaf(sc[0][r], 0.125f, mk0);
      s1[r] = fmaf(sc[1][r], 0.125f, mk1);
      rmax[r] = fmaxf(s0[r], s1[r]);
    }
    #pragma unroll
    for (int off = 1; off < 16; off <<= 1){
      #pragma unroll
      for (int r = 0; r < 4; ++r) rmax[r] = fmaxf(rmax[r], __shfl_xor(rmax[r], off, 16));
    }
    float corr[4];
    #pragma unroll
    for (int r = 0; r < 4; ++r){
      float mn = fmaxf(m_run[r], rmax[r]);
      corr[r] = __expf(m_run[r] - mn);
      m_run[r] = mn;
      float p0 = __expf(s0[r] - mn);
      float p1 = __expf(s1[r] - mn);
      unsigned short pb0 = f2bf(p0), pb1 = f2bf(p1);
      l_run[r] = l_run[r]*corr[r] + bf2f(pb0) + bf2f(pb1);
      P[w][4*lg + r][lr]      = pb0;
      P[w][4*lg + r][16 + lr] = pb1;
    }
    #pragma unroll
    for (int d4 = 0; d4 < 4; ++d4)
      #pragma unroll
      for (int r = 0; r < 4; ++r) acc[d4][r] *= corr[r];
    short8 pf = *(const short8*)&P[w][lr][lg*8];
    #pragma unroll
    for (int d4 = 0; d4 < 4; ++d4){
      size_t voff = ((size_t)(b*HH + hoff + d4*16 + lr))*SS + kv + lg*8;
      short8 vf = *(const short8*)(vt + voff);
      acc[d4] = __builtin_amdgcn_mfma_f32_16x16x32_bf16(pf, vf, acc[d4], 0, 0, 0);
    }
  }
  #pragma unroll
  for (int off = 1; off < 16; off <<= 1){
    #pragma unroll
    for (int r = 0; r < 4; ++r) l_run[r] += __shfl_xor(l_run[r], off, 16);
  }
  #pragma unroll
  for (int r = 0; r < 4; ++r) l_run[r] = 1.0f / l_run[r];
  #pragma unroll
  for (int d4 = 0; d4 < 4; ++d4)
    #pragma unroll
    for (int r = 0; r < 4; ++r){
      size_t o = ((size_t)(b*SS + q0 + 4*lg + r))*HH + hoff + d4*16 + lr;
      ao[o] = f2bf(acc[d4][r] * l_run[r]);
    }
}

// ---------------- launcher ----------------
extern "C" void kernel_launch(void* const* d_in, const int* in_sizes, int n_in,
                              void* d_out, int out_size, void* d_ws, size_t ws_size,
                              hipStream_t stream)
{
  const float* hs  = (const float*)d_in[0];
  const float* msk = (const float*)d_in[1];
  const float* qs  = (const float*)d_in[2];
  const float* qd  = (const float*)d_in[3];
  const float* ks  = (const float*)d_in[4];
  const float* kd  = (const float*)d_in[5];
  const float* vs  = (const float*)d_in[6];
  const float* vd  = (const float*)d_in[7];
  const float* os_ = (const float*)d_in[8];
  const float* od  = (const float*)d_in[9];
  float* out = (float*)d_out;

  const size_t NHS = (size_t)MM * HH;  // 4M elems
  const size_t NW  = (size_t)HH * HH;  // 1M elems
  unsigned short* p = (unsigned short*)d_ws;
  unsigned short* hsh = p; p += NHS;
  unsigned short* hsl = p; p += NHS;
  unsigned short* wqh = p; p += NW;
  unsigned short* wql = p; p += NW;
  unsigned short* wkh = p; p += NW;
  unsigned short* wkl = p; p += NW;
  unsigned short* wv  = p; p += NW;
  unsigned short* wo  = p; p += NW;
  unsigned short* qhB = p; p += NHS;
  unsigned short* qlB = p; p += NHS;
  unsigned short* khB = p; p += NHS;
  unsigned short* klB = p; p += NHS;
  unsigned short* vtB = p; p += NHS;
  unsigned short* aoB = p; p += NHS;
  // total: 38M elems * 2B = 76 MB of d_ws

  k_split  <<<(int)(NHS/1024), 256, 0, stream>>>(hs, hsh, hsl, (int)(NHS/4));
  k_addsplit<<<(int)(NW/1024), 256, 0, stream>>>(qs, qd, wqh, wql, (int)(NW/4));
  k_addsplit<<<(int)(NW/1024), 256, 0, stream>>>(ks, kd, wkh, wkl, (int)(NW/4));
  k_addplain<<<(int)(NW/1024), 256, 0, stream>>>(vs, vd, wv, (int)(NW/4));
  k_addplain<<<(int)(NW/1024), 256, 0, stream>>>(os_, od, wo, (int)(NW/4));

  dim3 gg(HH/128, MM/128);   // (8, 32)
  gemm_bt_split<<<gg, 256, 0, stream>>>(hsh, hsl, wqh, wql, qhB, qlB, MM, HH, HH);
  gemm_bt_split<<<gg, 256, 0, stream>>>(hsh, hsl, wkh, wkl, khB, klB, MM, HH, HH);
  gemm_bt<1><<<gg, 256, 0, stream>>>(hsh, wv, (void*)vtB, MM, HH, HH);

  attn_fwd<<<BB*NHH*(SS/64), 256, 0, stream>>>(qhB, qlB, khB, klB, vtB, msk, aoB);

  gemm_bt<2><<<gg, 256, 0, stream>>>(aoB, wo, (void*)out, MM, HH, HH);
}

// Round 2
// 365.159 us; speedup vs baseline: 1.6982x; 1.6982x over previous
//
#include <hip/hip_runtime.h>
#include <hip/hip_bf16.h>
#include <stdint.h>

#define BB 2
#define SS 2048
#define HH 1024
#define NHH 16
#define HDD 64
#define MM (BB*SS)   // 4096

typedef __attribute__((ext_vector_type(8))) short short8;
typedef __attribute__((ext_vector_type(4))) float f32x4;
typedef __attribute__((ext_vector_type(4))) unsigned short u16x4;

__device__ __forceinline__ unsigned short f2bf(float x){
  unsigned u = __float_as_uint(x);
  u += 0x7fffu + ((u >> 16) & 1u);   // RNE; inputs are finite
  return (unsigned short)(u >> 16);
}
__device__ __forceinline__ float bf2f(unsigned short h){
  return __uint_as_float(((unsigned)h) << 16);
}

// ---------------- conversion kernels ----------------
__global__ void k_split(const float* __restrict__ in, unsigned short* __restrict__ hi,
                        unsigned short* __restrict__ lo, int n4){
  int i = blockIdx.x * blockDim.x + threadIdx.x;
  if (i >= n4) return;
  f32x4 x = ((const f32x4*)in)[i];
  u16x4 h, l;
  #pragma unroll
  for (int j = 0; j < 4; ++j){
    unsigned short hb = f2bf(x[j]);
    h[j] = hb;
    l[j] = f2bf(x[j] - bf2f(hb));
  }
  ((u16x4*)hi)[i] = h;
  ((u16x4*)lo)[i] = l;
}

__global__ void k_addsplit(const float* __restrict__ a, const float* __restrict__ b,
                           unsigned short* __restrict__ hi, unsigned short* __restrict__ lo, int n4){
  int i = blockIdx.x * blockDim.x + threadIdx.x;
  if (i >= n4) return;
  f32x4 x = ((const f32x4*)a)[i] + ((const f32x4*)b)[i];
  u16x4 h, l;
  #pragma unroll
  for (int j = 0; j < 4; ++j){
    unsigned short hb = f2bf(x[j]);
    h[j] = hb;
    l[j] = f2bf(x[j] - bf2f(hb));
  }
  ((u16x4*)hi)[i] = h;
  ((u16x4*)lo)[i] = l;
}

__global__ void k_addplain(const float* __restrict__ a, const float* __restrict__ b,
                           unsigned short* __restrict__ w, int n4){
  int i = blockIdx.x * blockDim.x + threadIdx.x;
  if (i >= n4) return;
  f32x4 x = ((const f32x4*)a)[i] + ((const f32x4*)b)[i];
  u16x4 h;
  #pragma unroll
  for (int j = 0; j < 4; ++j) h[j] = f2bf(x[j]);
  ((u16x4*)w)[i] = h;
}

// ---------------- plain GEMM: C[M,N] = A[M,K] * B[N,K]^T ----------------
// EPI==1: bf16 output written transposed per-head as vT[(b*HH + n)*SS + s]
// EPI==2: fp32 output C[M,N]
template<int EPI>
__global__ __launch_bounds__(256, 2)
void gemm_bt(const unsigned short* __restrict__ A, const unsigned short* __restrict__ Bm,
             void* __restrict__ Cout, int M, int N, int K)
{
  __shared__ unsigned short As[128*32];
  __shared__ unsigned short Bs[128*32];
  const int tid = threadIdx.x;
  const int mb0 = blockIdx.y * 128, nb0 = blockIdx.x * 128;
  const int w  = tid >> 6, lane = tid & 63;
  const int wr = w >> 1,  wc = w & 1;
  const int lg = lane >> 4, lr = lane & 15;

  f32x4 zero4 = {0.f, 0.f, 0.f, 0.f};
  f32x4 acc[4][4];
  #pragma unroll
  for (int mi = 0; mi < 4; ++mi)
    #pragma unroll
    for (int ni = 0; ni < 4; ++ni) acc[mi][ni] = zero4;

  const unsigned short* Abase = A  + (size_t)mb0 * K;
  const unsigned short* Bbase = Bm + (size_t)nb0 * K;

  for (int kb = 0; kb < K; kb += 32) {
    __syncthreads();
    #pragma unroll
    for (int i = 0; i < 2; ++i){
      int c = i*256 + tid;
      int row = c >> 2, off = (c & 3) << 3;
      size_t go = (size_t)row * K + kb + off;
      __builtin_amdgcn_global_load_lds(
          (const __attribute__((address_space(1))) void*)(Abase + go),
          (__attribute__((address_space(3))) void*)(&As[c*8]), 16, 0, 0);
      __builtin_amdgcn_global_load_lds(
          (const __attribute__((address_space(1))) void*)(Bbase + go),
          (__attribute__((address_space(3))) void*)(&Bs[c*8]), 16, 0, 0);
    }
    __syncthreads();
    short8 af[4], bfr[4];
    #pragma unroll
    for (int mi = 0; mi < 4; ++mi) af[mi]  = *(const short8*)&As[(wr*64 + mi*16 + lr)*32 + lg*8];
    #pragma unroll
    for (int ni = 0; ni < 4; ++ni) bfr[ni] = *(const short8*)&Bs[(wc*64 + ni*16 + lr)*32 + lg*8];
    #pragma unroll
    for (int mi = 0; mi < 4; ++mi)
      #pragma unroll
      for (int ni = 0; ni < 4; ++ni)
        acc[mi][ni] = __builtin_amdgcn_mfma_f32_16x16x32_bf16(af[mi], bfr[ni], acc[mi][ni], 0, 0, 0);
  }

  #pragma unroll
  for (int mi = 0; mi < 4; ++mi){
    #pragma unroll
    for (int ni = 0; ni < 4; ++ni){
      int n  = nb0 + wc*64 + ni*16 + lr;
      int m0 = mb0 + wr*64 + mi*16 + 4*lg;
      if constexpr (EPI == 1) {
        unsigned short* vt = (unsigned short*)Cout;
        int b = m0 >> 11, s0 = m0 & 2047;
        u16x4 pk;
        #pragma unroll
        for (int r = 0; r < 4; ++r) pk[r] = f2bf(acc[mi][ni][r]);
        *(u16x4*)&vt[((size_t)(b*HH + n))*SS + s0] = pk;
      } else {
        float* C = (float*)Cout;
        #pragma unroll
        for (int r = 0; r < 4; ++r) C[(size_t)(m0 + r)*N + n] = acc[mi][ni][r];
      }
    }
  }
}

// ---------------- split GEMM (fp32-grade): C = (Ah+Al) * (Bh+Bl)^T, drop Al*Bl ----------------
__global__ __launch_bounds__(256, 2)
void gemm_bt_split(const unsigned short* __restrict__ Ah, const unsigned short* __restrict__ Al,
                   const unsigned short* __restrict__ Bh, const unsigned short* __restrict__ Bl,
                   unsigned short* __restrict__ Ch, unsigned short* __restrict__ Cl,
                   int M, int N, int K)
{
  __shared__ unsigned short Ash[128*32], Asl[128*32], Bsh[128*32], Bsl[128*32];
  const int tid = threadIdx.x;
  const int mb0 = blockIdx.y * 128, nb0 = blockIdx.x * 128;
  const int w  = tid >> 6, lane = tid & 63;
  const int wr = w >> 1,  wc = w & 1;
  const int lg = lane >> 4, lr = lane & 15;

  f32x4 zero4 = {0.f, 0.f, 0.f, 0.f};
  f32x4 acc[4][4];
  #pragma unroll
  for (int mi = 0; mi < 4; ++mi)
    #pragma unroll
    for (int ni = 0; ni < 4; ++ni) acc[mi][ni] = zero4;

  const unsigned short* Ahb = Ah + (size_t)mb0 * K;
  const unsigned short* Alb = Al + (size_t)mb0 * K;
  const unsigned short* Bhb = Bh + (size_t)nb0 * K;
  const unsigned short* Blb = Bl + (size_t)nb0 * K;

  for (int kb = 0; kb < K; kb += 32) {
    __syncthreads();
    #pragma unroll
    for (int i = 0; i < 2; ++i){
      int c = i*256 + tid;
      int row = c >> 2, off = (c & 3) << 3;
      size_t go = (size_t)row * K + kb + off;
      __builtin_amdgcn_global_load_lds(
          (const __attribute__((address_space(1))) void*)(Ahb + go),
          (__attribute__((address_space(3))) void*)(&Ash[c*8]), 16, 0, 0);
      __builtin_amdgcn_global_load_lds(
          (const __attribute__((address_space(1))) void*)(Alb + go),
          (__attribute__((address_space(3))) void*)(&Asl[c*8]), 16, 0, 0);
      __builtin_amdgcn_global_load_lds(
          (const __attribute__((address_space(1))) void*)(Bhb + go),
          (__attribute__((address_space(3))) void*)(&Bsh[c*8]), 16, 0, 0);
      __builtin_amdgcn_global_load_lds(
          (const __attribute__((address_space(1))) void*)(Blb + go),
          (__attribute__((address_space(3))) void*)(&Bsl[c*8]), 16, 0, 0);
    }
    __syncthreads();
    short8 ah4[4], al4[4], bh4[4], bl4[4];
    #pragma unroll
    for (int mi = 0; mi < 4; ++mi){
      int ro = (wr*64 + mi*16 + lr)*32 + lg*8;
      ah4[mi] = *(const short8*)&Ash[ro];
      al4[mi] = *(const short8*)&Asl[ro];
    }
    #pragma unroll
    for (int ni = 0; ni < 4; ++ni){
      int ro = (wc*64 + ni*16 + lr)*32 + lg*8;
      bh4[ni] = *(const short8*)&Bsh[ro];
      bl4[ni] = *(const short8*)&Bsl[ro];
    }
    #pragma unroll
    for (int mi = 0; mi < 4; ++mi)
      #pragma unroll
      for (int ni = 0; ni < 4; ++ni){
        acc[mi][ni] = __builtin_amdgcn_mfma_f32_16x16x32_bf16(ah4[mi], bh4[ni], acc[mi][ni], 0, 0, 0);
        acc[mi][ni] = __builtin_amdgcn_mfma_f32_16x16x32_bf16(al4[mi], bh4[ni], acc[mi][ni], 0, 0, 0);
        acc[mi][ni] = __builtin_amdgcn_mfma_f32_16x16x32_bf16(ah4[mi], bl4[ni], acc[mi][ni], 0, 0, 0);
      }
  }

  #pragma unroll
  for (int mi = 0; mi < 4; ++mi){
    #pragma unroll
    for (int ni = 0; ni < 4; ++ni){
      int n  = nb0 + wc*64 + ni*16 + lr;
      int m0 = mb0 + wr*64 + mi*16 + 4*lg;
      #pragma unroll
      for (int r = 0; r < 4; ++r){
        float x = acc[mi][ni][r];
        unsigned short hb = f2bf(x);
        unsigned short lb = f2bf(x - bf2f(hb));
        size_t o = (size_t)(m0 + r)*N + n;
        Ch[o] = hb;
        Cl[o] = lb;
      }
    }
  }
}

// ---------------- flash attention (v2) ----------------
// 512 thr = 8 waves; block covers 128 q-rows of one (b,h); wave w owns 16 rows.
// KVBLK=64. K-hi/K-lo/V^T staged in LDS (shared by all 8 waves), double-buffered
// via global_load_lds, XOR-swizzled (linear LDS dest + inverse-swizzled global
// source + swizzled ds_read — rule #21). One __syncthreads per step at the TOP,
// stage for t+1 issued right after it so HBM latency hides under compute.
// LDS: 3*2*8KB (K/Kl/V dbuf) + 8*2KB (per-wave P) = 64KB -> 2 blocks/CU.
__global__ __launch_bounds__(512, 4)
void attn_fwd(const unsigned short* __restrict__ qh, const unsigned short* __restrict__ ql,
              const unsigned short* __restrict__ kh, const unsigned short* __restrict__ kl,
              const unsigned short* __restrict__ vt, const float* __restrict__ mask,
              unsigned short* __restrict__ ao)
{
  __shared__ unsigned short Ksh[2][64*64];
  __shared__ unsigned short Ksl[2][64*64];
  __shared__ unsigned short Vss[2][64*64];
  __shared__ unsigned short P[8][16*64];

  const int tid = threadIdx.x;
  const int w = tid >> 6, lane = tid & 63;
  const int lg = lane >> 4, lr = lane & 15;
  const int xork = (lr & 7) << 4;           // byte-XOR for swizzled ds_read

  // XCD-aware bijective remap (512 % 8 == 0): blocks sharing one (b,h) -> one XCD
  const int bid = (blockIdx.x & 7) * 64 + (blockIdx.x >> 3);
  const int qb = bid & 15, h = (bid >> 4) & 15, b = bid >> 8;
  const int q0 = qb*128 + w*16;
  const int hoff = h*64;

  // staging role of this thread: row srow (key idx or d idx), 16B granule sg
  const int srow = tid >> 3;                // 0..63
  const int sgx  = (tid & 7) ^ (srow & 7);  // inverse-swizzled source granule

  short8 qfh[2], qfl[2];
  {
    size_t qoff = ((size_t)(b*SS + q0 + lr))*HH + hoff + lg*8;
    qfh[0] = *(const short8*)(qh + qoff);
    qfl[0] = *(const short8*)(ql + qoff);
    qfh[1] = *(const short8*)(qh + qoff + 32);
    qfl[1] = *(const short8*)(ql + qoff + 32);
  }

  float m_run[4] = {-1e30f, -1e30f, -1e30f, -1e30f};
  float l_run[4] = {0.f, 0.f, 0.f, 0.f};
  f32x4 zero4 = {0.f, 0.f, 0.f, 0.f};
  f32x4 acc[4];
  #pragma unroll
  for (int d4 = 0; d4 < 4; ++d4) acc[d4] = zero4;
  const size_t mrow = ((size_t)(b*SS + q0 + 4*lg))*SS;

  #define ATTN_STAGE(buf, kvb) do {                                              \
    size_t kro = ((size_t)(b*SS + (kvb) + srow))*HH + hoff + sgx*8;              \
    size_t vro = ((size_t)(b*HH + hoff + srow))*SS + (kvb) + sgx*8;              \
    __builtin_amdgcn_global_load_lds(                                            \
        (const __attribute__((address_space(1))) void*)(kh + kro),               \
        (__attribute__((address_space(3))) void*)(&Ksh[buf][tid*8]), 16, 0, 0);  \
    __builtin_amdgcn_global_load_lds(                                            \
        (const __attribute__((address_space(1))) void*)(kl + kro),               \
        (__attribute__((address_space(3))) void*)(&Ksl[buf][tid*8]), 16, 0, 0);  \
    __builtin_amdgcn_global_load_lds(                                            \
        (const __attribute__((address_space(1))) void*)(vt + vro),               \
        (__attribute__((address_space(3))) void*)(&Vss[buf][tid*8]), 16, 0, 0);  \
  } while (0)

  ATTN_STAGE(0, 0);

  for (int t = 0; t < SS/64; ++t) {
    const int kv = t*64;
    const int cur = t & 1;
    __syncthreads();                       // drains stage for buf[cur]; WAR-safe
    if (t + 1 < SS/64) ATTN_STAGE(cur ^ 1, kv + 64);

    // mask prefetch into regs (consumed after QK MFMAs)
    float mk[4][4];
    #pragma unroll
    for (int r = 0; r < 4; ++r)
      #pragma unroll
      for (int nb = 0; nb < 4; ++nb)
        mk[r][nb] = mask[mrow + (size_t)r*SS + kv + nb*16 + lr];

    // QK^T: 3-term split over d=64 (2 chunks of 32)
    f32x4 sc[4];
    #pragma unroll
    for (int nb = 0; nb < 4; ++nb) {
      const int krow = (nb*16 + lr)*64;
      const int c0 = ((0   + lg*16) ^ xork) >> 1;
      const int c1 = ((64  + lg*16) ^ xork) >> 1;
      short8 k0h = *(const short8*)&Ksh[cur][krow + c0];
      short8 k1h = *(const short8*)&Ksh[cur][krow + c1];
      short8 k0l = *(const short8*)&Ksl[cur][krow + c0];
      short8 k1l = *(const short8*)&Ksl[cur][krow + c1];
      f32x4 d = zero4;
      d = __builtin_amdgcn_mfma_f32_16x16x32_bf16(qfh[0], k0h, d, 0, 0, 0);
      d = __builtin_amdgcn_mfma_f32_16x16x32_bf16(qfh[1], k1h, d, 0, 0, 0);
      d = __builtin_amdgcn_mfma_f32_16x16x32_bf16(qfh[0], k0l, d, 0, 0, 0);
      d = __builtin_amdgcn_mfma_f32_16x16x32_bf16(qfh[1], k1l, d, 0, 0, 0);
      d = __builtin_amdgcn_mfma_f32_16x16x32_bf16(qfl[0], k0h, d, 0, 0, 0);
      d = __builtin_amdgcn_mfma_f32_16x16x32_bf16(qfl[1], k1h, d, 0, 0, 0);
      sc[nb] = d;
    }

    // softmax (online), 16 q-rows per wave, 64 keys this step
    float s[4][4], rmax[4];
    #pragma unroll
    for (int r = 0; r < 4; ++r) {
      float a0 = fmaf(sc[0][r], 0.125f, mk[r][0]);
      float a1 = fmaf(sc[1][r], 0.125f, mk[r][1]);
      float a2 = fmaf(sc[2][r], 0.125f, mk[r][2]);
      float a3 = fmaf(sc[3][r], 0.125f, mk[r][3]);
      s[0][r] = a0; s[1][r] = a1; s[2][r] = a2; s[3][r] = a3;
      rmax[r] = fmaxf(fmaxf(a0, a1), fmaxf(a2, a3));
    }
    #pragma unroll
    for (int off = 1; off < 16; off <<= 1) {
      #pragma unroll
      for (int r = 0; r < 4; ++r) rmax[r] = fmaxf(rmax[r], __shfl_xor(rmax[r], off, 16));
    }
    float corr[4];
    #pragma unroll
    for (int r = 0; r < 4; ++r) {
      float mn = fmaxf(m_run[r], rmax[r]);
      corr[r] = __expf(m_run[r] - mn);
      m_run[r] = mn;
      const int prow = 4*lg + r;
      const int pxor = (prow & 7) << 4;
      float lsum = 0.f;
      #pragma unroll
      for (int nb = 0; nb < 4; ++nb) {
        float pv = __expf(s[nb][r] - mn);
        unsigned short pb = f2bf(pv);
        lsum += bf2f(pb);
        P[w][prow*64 + (((((nb*16 + lr) << 1)) ^ pxor) >> 1)] = pb;
      }
      l_run[r] = l_run[r]*corr[r] + lsum;
    }
    #pragma unroll
    for (int d4 = 0; d4 < 4; ++d4)
      #pragma unroll
      for (int r = 0; r < 4; ++r) acc[d4][r] *= corr[r];

    // PV: P[16 q x 64 k] * V^T[64 d x 64 k]
    const int p0 = ((0  + lg*16) ^ xork) >> 1;
    const int p1 = ((64 + lg*16) ^ xork) >> 1;
    short8 pf0 = *(const short8*)&P[w][lr*64 + p0];
    short8 pf1 = *(const short8*)&P[w][lr*64 + p1];
    #pragma unroll
    for (int d4 = 0; d4 < 4; ++d4) {
      const int vrow = (d4*16 + lr)*64;
      short8 vf0 = *(const short8*)&Vss[cur][vrow + p0];
      short8 vf1 = *(const short8*)&Vss[cur][vrow + p1];
      acc[d4] = __builtin_amdgcn_mfma_f32_16x16x32_bf16(pf0, vf0, acc[d4], 0, 0, 0);
      acc[d4] = __builtin_amdgcn_mfma_f32_16x16x32_bf16(pf1, vf1, acc[d4], 0, 0, 0);
    }
  }
  #undef ATTN_STAGE

  #pragma unroll
  for (int off = 1; off < 16; off <<= 1) {
    #pragma unroll
    for (int r = 0; r < 4; ++r) l_run[r] += __shfl_xor(l_run[r], off, 16);
  }
  #pragma unroll
  for (int r = 0; r < 4; ++r) l_run[r] = 1.0f / l_run[r];
  #pragma unroll
  for (int d4 = 0; d4 < 4; ++d4)
    #pragma unroll
    for (int r = 0; r < 4; ++r) {
      size_t o = ((size_t)(b*SS + q0 + 4*lg + r))*HH + hoff + d4*16 + lr;
      ao[o] = f2bf(acc[d4][r] * l_run[r]);
    }
}

// ---------------- launcher ----------------
extern "C" void kernel_launch(void* const* d_in, const int* in_sizes, int n_in,
                              void* d_out, int out_size, void* d_ws, size_t ws_size,
                              hipStream_t stream)
{
  const float* hs  = (const float*)d_in[0];
  const float* msk = (const float*)d_in[1];
  const float* qs  = (const float*)d_in[2];
  const float* qd  = (const float*)d_in[3];
  const float* ks  = (const float*)d_in[4];
  const float* kd  = (const float*)d_in[5];
  const float* vs  = (const float*)d_in[6];
  const float* vd  = (const float*)d_in[7];
  const float* os_ = (const float*)d_in[8];
  const float* od  = (const float*)d_in[9];
  float* out = (float*)d_out;

  const size_t NHS = (size_t)MM * HH;  // 4M elems
  const size_t NW  = (size_t)HH * HH;  // 1M elems
  unsigned short* p = (unsigned short*)d_ws;
  unsigned short* hsh = p; p += NHS;
  unsigned short* hsl = p; p += NHS;
  unsigned short* wqh = p; p += NW;
  unsigned short* wql = p; p += NW;
  unsigned short* wkh = p; p += NW;
  unsigned short* wkl = p; p += NW;
  unsigned short* wv  = p; p += NW;
  unsigned short* wo  = p; p += NW;
  unsigned short* qhB = p; p += NHS;
  unsigned short* qlB = p; p += NHS;
  unsigned short* khB = p; p += NHS;
  unsigned short* klB = p; p += NHS;
  unsigned short* vtB = p; p += NHS;
  unsigned short* aoB = p; p += NHS;
  // total: 38M elems * 2B = 76 MB of d_ws

  k_split  <<<(int)(NHS/1024), 256, 0, stream>>>(hs, hsh, hsl, (int)(NHS/4));
  k_addsplit<<<(int)(NW/1024), 256, 0, stream>>>(qs, qd, wqh, wql, (int)(NW/4));
  k_addsplit<<<(int)(NW/1024), 256, 0, stream>>>(ks, kd, wkh, wkl, (int)(NW/4));
  k_addplain<<<(int)(NW/1024), 256, 0, stream>>>(vs, vd, wv, (int)(NW/4));
  k_addplain<<<(int)(NW/1024), 256, 0, stream>>>(os_, od, wo, (int)(NW/4));

  dim3 gg(HH/128, MM/128);   // (8, 32)
  gemm_bt_split<<<gg, 256, 0, stream>>>(hsh, hsl, wqh, wql, qhB, qlB, MM, HH, HH);
  gemm_bt_split<<<gg, 256, 0, stream>>>(hsh, hsl, wkh, wkl, khB, klB, MM, HH, HH);
  gemm_bt<1><<<gg, 256, 0, stream>>>(hsh, wv, (void*)vtB, MM, HH, HH);

  attn_fwd<<<BB*NHH*(SS/128), 512, 0, stream>>>(qhB, qlB, khB, klB, vtB, msk, aoB);

  gemm_bt<2><<<gg, 256, 0, stream>>>(aoB, wo, (void*)out, MM, HH, HH);
}

// Round 3
// 353.693 us; speedup vs baseline: 1.7533x; 1.0324x over previous
//
#include <hip/hip_runtime.h>
#include <hip/hip_bf16.h>
#include <stdint.h>

#define BB 2
#define SS 2048
#define HH 1024
#define NHH 16
#define HDD 64
#define MM (BB*SS)   // 4096
#define N4SEG (HH*HH/4)   // 262144 = 2^18

typedef __attribute__((ext_vector_type(8))) short short8;
typedef __attribute__((ext_vector_type(4))) float f32x4;
typedef __attribute__((ext_vector_type(4))) unsigned short u16x4;

__device__ __forceinline__ unsigned short f2bf(float x){
  unsigned u = __float_as_uint(x);
  u += 0x7fffu + ((u >> 16) & 1u);   // RNE; inputs are finite
  return (unsigned short)(u >> 16);
}
__device__ __forceinline__ float bf2f(unsigned short h){
  return __uint_as_float(((unsigned)h) << 16);
}
__device__ __forceinline__ unsigned short f2bf_fast(float x){
  __hip_bfloat16 hb = __float2bfloat16(x);   // compiler emits v_cvt (pairs -> cvt_pk)
  return *reinterpret_cast<unsigned short*>(&hb);
}

// ---------------- conversion kernels ----------------
__global__ void k_split(const float* __restrict__ in, unsigned short* __restrict__ hi,
                        unsigned short* __restrict__ lo, int n4){
  int i = blockIdx.x * blockDim.x + threadIdx.x;
  if (i >= n4) return;
  f32x4 x = ((const f32x4*)in)[i];
  u16x4 h, l;
  #pragma unroll
  for (int j = 0; j < 4; ++j){
    unsigned short hb = f2bf(x[j]);
    h[j] = hb;
    l[j] = f2bf(x[j] - bf2f(hb));
  }
  ((u16x4*)hi)[i] = h;
  ((u16x4*)lo)[i] = l;
}

// all 4 weight preps in one launch: seg 0: q(split) 1: k(split) 2: v(plain) 3: o(plain)
__global__ void k_wprep(const float* __restrict__ qs, const float* __restrict__ qd,
                        const float* __restrict__ ks, const float* __restrict__ kd,
                        const float* __restrict__ vs, const float* __restrict__ vd,
                        const float* __restrict__ os_, const float* __restrict__ od,
                        unsigned short* __restrict__ wqh, unsigned short* __restrict__ wql,
                        unsigned short* __restrict__ wkh, unsigned short* __restrict__ wkl,
                        unsigned short* __restrict__ wv,  unsigned short* __restrict__ wo){
  int i = blockIdx.x * blockDim.x + threadIdx.x;
  int seg = i >> 18;
  int j = i & (N4SEG - 1);
  const float *pa, *pb; unsigned short *ph, *pl = nullptr;
  if      (seg == 0){ pa = qs; pb = qd; ph = wqh; pl = wql; }
  else if (seg == 1){ pa = ks; pb = kd; ph = wkh; pl = wkl; }
  else if (seg == 2){ pa = vs; pb = vd; ph = wv; }
  else              { pa = os_; pb = od; ph = wo; }
  f32x4 x = ((const f32x4*)pa)[j] + ((const f32x4*)pb)[j];
  u16x4 h, l;
  #pragma unroll
  for (int c = 0; c < 4; ++c){
    unsigned short hb = f2bf(x[c]);
    h[c] = hb;
    l[c] = f2bf(x[c] - bf2f(hb));
  }
  ((u16x4*)ph)[j] = h;
  if (pl) ((u16x4*)pl)[j] = l;
}

// mask permute: pm[((b*32+t)*2048+q)*64 + lr*4 + nb] = mask[(b*2048+q)*2048 + t*64 + nb*16 + lr]
__global__ void k_maskperm(const float* __restrict__ m, float* __restrict__ pm){
  int i = blockIdx.x * blockDim.x + threadIdx.x;   // one f32x4 out per thread
  int lr = i & 15;
  int q  = (i >> 4) & 2047;
  int t  = (i >> 15) & 31;
  int b  = i >> 20;
  const float* src = m + ((size_t)(b*2048 + q))*2048 + t*64 + lr;
  f32x4 v = { src[0], src[16], src[32], src[48] };
  ((f32x4*)pm)[i] = v;
}

// ---------------- fused QKV projection ----------------
// C-cols [0,1024)=q(split), [1024,2048)=k(split), [2048,3072)=v(plain, vT epilogue).
// 128x128 tiles, BK=32, global_load_lds w16, grid 24x32 = 768 blocks (~3/CU).
__global__ __launch_bounds__(256, 2)
void proj_fused(const unsigned short* __restrict__ hsh, const unsigned short* __restrict__ hsl,
                const unsigned short* __restrict__ wqh, const unsigned short* __restrict__ wql,
                const unsigned short* __restrict__ wkh, const unsigned short* __restrict__ wkl,
                const unsigned short* __restrict__ wv,
                unsigned short* __restrict__ qhB, unsigned short* __restrict__ qlB,
                unsigned short* __restrict__ khB, unsigned short* __restrict__ klB,
                unsigned short* __restrict__ vtB)
{
  __shared__ unsigned short Ash[128*32], Asl[128*32], Bsh[128*32], Bsl[128*32];
  const int tid = threadIdx.x;
  const int nb0 = blockIdx.x * 128;        // 0..3071
  const int mb0 = blockIdx.y * 128;
  const int kind = nb0 >> 10;              // 0=q 1=k 2=v
  const int ncol0 = nb0 & 1023;
  const int w  = tid >> 6, lane = tid & 63;
  const int wr = w >> 1,  wc = w & 1;
  const int lg = lane >> 4, lr = lane & 15;

  const unsigned short* Bh = (kind == 0 ? wqh : (kind == 1 ? wkh : wv)) + (size_t)ncol0 * HH;
  const unsigned short* Bl = (kind == 0 ? wql : wkl) + (size_t)ncol0 * HH;  // unused for v
  const unsigned short* Ahb = hsh + (size_t)mb0 * HH;
  const unsigned short* Alb = hsl + (size_t)mb0 * HH;

  f32x4 zero4 = {0.f, 0.f, 0.f, 0.f};
  f32x4 acc[4][4];
  #pragma unroll
  for (int mi = 0; mi < 4; ++mi)
    #pragma unroll
    for (int ni = 0; ni < 4; ++ni) acc[mi][ni] = zero4;

  for (int kb = 0; kb < HH; kb += 32) {
    __syncthreads();
    #pragma unroll
    for (int i = 0; i < 2; ++i){
      int c = i*256 + tid;
      int row = c >> 2, off = (c & 3) << 3;
      size_t go = (size_t)row * HH + kb + off;
      __builtin_amdgcn_global_load_lds(
          (const __attribute__((address_space(1))) void*)(Ahb + go),
          (__attribute__((address_space(3))) void*)(&Ash[c*8]), 16, 0, 0);
      __builtin_amdgcn_global_load_lds(
          (const __attribute__((address_space(1))) void*)(Alb + go),
          (__attribute__((address_space(3))) void*)(&Asl[c*8]), 16, 0, 0);
      __builtin_amdgcn_global_load_lds(
          (const __attribute__((address_space(1))) void*)(Bh + go),
          (__attribute__((address_space(3))) void*)(&Bsh[c*8]), 16, 0, 0);
      if (kind < 2)
        __builtin_amdgcn_global_load_lds(
            (const __attribute__((address_space(1))) void*)(Bl + go),
            (__attribute__((address_space(3))) void*)(&Bsl[c*8]), 16, 0, 0);
    }
    __syncthreads();
    short8 ah4[4], al4[4], bh4[4], bl4[4];
    #pragma unroll
    for (int mi = 0; mi < 4; ++mi){
      int ro = (wr*64 + mi*16 + lr)*32 + lg*8;
      ah4[mi] = *(const short8*)&Ash[ro];
      al4[mi] = *(const short8*)&Asl[ro];
    }
    #pragma unroll
    for (int ni = 0; ni < 4; ++ni){
      int ro = (wc*64 + ni*16 + lr)*32 + lg*8;
      bh4[ni] = *(const short8*)&Bsh[ro];
    }
    if (kind < 2) {
      #pragma unroll
      for (int ni = 0; ni < 4; ++ni){
        int ro = (wc*64 + ni*16 + lr)*32 + lg*8;
        bl4[ni] = *(const short8*)&Bsl[ro];
      }
      #pragma unroll
      for (int mi = 0; mi < 4; ++mi)
        #pragma unroll
        for (int ni = 0; ni < 4; ++ni){
          acc[mi][ni] = __builtin_amdgcn_mfma_f32_16x16x32_bf16(ah4[mi], bh4[ni], acc[mi][ni], 0, 0, 0);
          acc[mi][ni] = __builtin_amdgcn_mfma_f32_16x16x32_bf16(al4[mi], bh4[ni], acc[mi][ni], 0, 0, 0);
          acc[mi][ni] = __builtin_amdgcn_mfma_f32_16x16x32_bf16(ah4[mi], bl4[ni], acc[mi][ni], 0, 0, 0);
        }
    } else {
      #pragma unroll
      for (int mi = 0; mi < 4; ++mi)
        #pragma unroll
        for (int ni = 0; ni < 4; ++ni)
          acc[mi][ni] = __builtin_amdgcn_mfma_f32_16x16x32_bf16(ah4[mi], bh4[ni], acc[mi][ni], 0, 0, 0);
    }
  }

  if (kind == 2) {
    #pragma unroll
    for (int mi = 0; mi < 4; ++mi){
      #pragma unroll
      for (int ni = 0; ni < 4; ++ni){
        int nv = ncol0 + wc*64 + ni*16 + lr;
        int m0 = mb0 + wr*64 + mi*16 + 4*lg;
        int b = m0 >> 11, s0 = m0 & 2047;
        u16x4 pk;
        #pragma unroll
        for (int r = 0; r < 4; ++r) pk[r] = f2bf_fast(acc[mi][ni][r]);
        *(u16x4*)&vtB[((size_t)(b*HH + nv))*SS + s0] = pk;
      }
    }
  } else {
    unsigned short* Ch = (kind == 0) ? qhB : khB;
    unsigned short* Cl = (kind == 0) ? qlB : klB;
    #pragma unroll
    for (int mi = 0; mi < 4; ++mi){
      #pragma unroll
      for (int ni = 0; ni < 4; ++ni){
        int n  = ncol0 + wc*64 + ni*16 + lr;
        int m0 = mb0 + wr*64 + mi*16 + 4*lg;
        #pragma unroll
        for (int r = 0; r < 4; ++r){
          float x = acc[mi][ni][r];
          unsigned short hb = f2bf(x);
          unsigned short lb = f2bf(x - bf2f(hb));
          size_t o = (size_t)(m0 + r)*HH + n;
          Ch[o] = hb;
          Cl[o] = lb;
        }
      }
    }
  }
}

// ---------------- O-projection GEMM: out[M,N] fp32 = A[M,K]bf16 * B[N,K]^T bf16 ----------------
__global__ __launch_bounds__(256, 2)
void gemm_o(const unsigned short* __restrict__ A, const unsigned short* __restrict__ Bm,
            float* __restrict__ C, int M, int N, int K)
{
  __shared__ unsigned short As[128*32];
  __shared__ unsigned short Bs[128*32];
  const int tid = threadIdx.x;
  const int mb0 = blockIdx.y * 128, nb0 = blockIdx.x * 128;
  const int w  = tid >> 6, lane = tid & 63;
  const int wr = w >> 1,  wc = w & 1;
  const int lg = lane >> 4, lr = lane & 15;

  f32x4 zero4 = {0.f, 0.f, 0.f, 0.f};
  f32x4 acc[4][4];
  #pragma unroll
  for (int mi = 0; mi < 4; ++mi)
    #pragma unroll
    for (int ni = 0; ni < 4; ++ni) acc[mi][ni] = zero4;

  const unsigned short* Abase = A  + (size_t)mb0 * K;
  const unsigned short* Bbase = Bm + (size_t)nb0 * K;

  for (int kb = 0; kb < K; kb += 32) {
    __syncthreads();
    #pragma unroll
    for (int i = 0; i < 2; ++i){
      int c = i*256 + tid;
      int row = c >> 2, off = (c & 3) << 3;
      size_t go = (size_t)row * K + kb + off;
      __builtin_amdgcn_global_load_lds(
          (const __attribute__((address_space(1))) void*)(Abase + go),
          (__attribute__((address_space(3))) void*)(&As[c*8]), 16, 0, 0);
      __builtin_amdgcn_global_load_lds(
          (const __attribute__((address_space(1))) void*)(Bbase + go),
          (__attribute__((address_space(3))) void*)(&Bs[c*8]), 16, 0, 0);
    }
    __syncthreads();
    short8 af[4], bfr[4];
    #pragma unroll
    for (int mi = 0; mi < 4; ++mi) af[mi]  = *(const short8*)&As[(wr*64 + mi*16 + lr)*32 + lg*8];
    #pragma unroll
    for (int ni = 0; ni < 4; ++ni) bfr[ni] = *(const short8*)&Bs[(wc*64 + ni*16 + lr)*32 + lg*8];
    #pragma unroll
    for (int mi = 0; mi < 4; ++mi)
      #pragma unroll
      for (int ni = 0; ni < 4; ++ni)
        acc[mi][ni] = __builtin_amdgcn_mfma_f32_16x16x32_bf16(af[mi], bfr[ni], acc[mi][ni], 0, 0, 0);
  }

  #pragma unroll
  for (int mi = 0; mi < 4; ++mi){
    #pragma unroll
    for (int ni = 0; ni < 4; ++ni){
      int n  = nb0 + wc*64 + ni*16 + lr;
      int m0 = mb0 + wr*64 + mi*16 + 4*lg;
      #pragma unroll
      for (int r = 0; r < 4; ++r) C[(size_t)(m0 + r)*N + n] = acc[mi][ni][r];
    }
  }
}

// ---------------- flash attention (v3) ----------------
// 512 thr = 8 waves; block = 128 q-rows of one (b,h); KVBLK=64; K/Kl/V^T LDS
// double-buffered via global_load_lds with both-sides XOR swizzle (rule #21).
// v3: mask pre-permuted fp32 (4 dwordx4/step), row-sums via MFMA-ones on the
// P fragments (drops per-step lsum VALU + final shuffle reduce).
__global__ __launch_bounds__(512, 4)
void attn_fwd(const unsigned short* __restrict__ qh, const unsigned short* __restrict__ ql,
              const unsigned short* __restrict__ kh, const unsigned short* __restrict__ kl,
              const unsigned short* __restrict__ vt, const float* __restrict__ pm,
              unsigned short* __restrict__ ao)
{
  __shared__ unsigned short Ksh[2][64*64];
  __shared__ unsigned short Ksl[2][64*64];
  __shared__ unsigned short Vss[2][64*64];
  __shared__ unsigned short P[8][16*64];

  const int tid = threadIdx.x;
  const int w = tid >> 6, lane = tid & 63;
  const int lg = lane >> 4, lr = lane & 15;
  const int xork = (lr & 7) << 4;

  // XCD-aware bijective remap (512 % 8 == 0)
  const int bid = (blockIdx.x & 7) * 64 + (blockIdx.x >> 3);
  const int qb = bid & 15, h = (bid >> 4) & 15, b = bid >> 8;
  const int q0 = qb*128 + w*16;
  const int hoff = h*64;

  const int srow = tid >> 3;
  const int sgx  = (tid & 7) ^ (srow & 7);

  short8 qfh[2], qfl[2];
  {
    size_t qoff = ((size_t)(b*SS + q0 + lr))*HH + hoff + lg*8;
    qfh[0] = *(const short8*)(qh + qoff);
    qfl[0] = *(const short8*)(ql + qoff);
    qfh[1] = *(const short8*)(qh + qoff + 32);
    qfl[1] = *(const short8*)(ql + qoff + 32);
  }
  short8 ones8;
  #pragma unroll
  for (int j = 0; j < 8; ++j) ones8[j] = (short)0x3F80;   // bf16 1.0

  float m_run[4] = {-1e30f, -1e30f, -1e30f, -1e30f};
  f32x4 zero4 = {0.f, 0.f, 0.f, 0.f};
  f32x4 acc[4], acc_l = zero4;
  #pragma unroll
  for (int d4 = 0; d4 < 4; ++d4) acc[d4] = zero4;

  const float* mbase = pm + ((size_t)b*32*2048 + q0 + 4*lg)*64 + (size_t)lr*4;

  #define ATTN_STAGE(buf, kvb) do {                                              \
    size_t kro = ((size_t)(b*SS + (kvb) + srow))*HH + hoff + sgx*8;              \
    size_t vro = ((size_t)(b*HH + hoff + srow))*SS + (kvb) + sgx*8;              \
    __builtin_amdgcn_global_load_lds(                                            \
        (const __attribute__((address_space(1))) void*)(kh + kro),               \
        (__attribute__((address_space(3))) void*)(&Ksh[buf][tid*8]), 16, 0, 0);  \
    __builtin_amdgcn_global_load_lds(                                            \
        (const __attribute__((address_space(1))) void*)(kl + kro),               \
        (__attribute__((address_space(3))) void*)(&Ksl[buf][tid*8]), 16, 0, 0);  \
    __builtin_amdgcn_global_load_lds(                                            \
        (const __attribute__((address_space(1))) void*)(vt + vro),               \
        (__attribute__((address_space(3))) void*)(&Vss[buf][tid*8]), 16, 0, 0);  \
  } while (0)

  ATTN_STAGE(0, 0);

  for (int t = 0; t < SS/64; ++t) {
    const int kv = t*64;
    const int cur = t & 1;
    __syncthreads();
    if (t + 1 < SS/64) ATTN_STAGE(cur ^ 1, kv + 64);

    // mask: 4 coalesced dwordx4 loads (pre-permuted)
    const float* mp = mbase + (size_t)t*(2048*64);
    f32x4 mk4[4];
    #pragma unroll
    for (int r = 0; r < 4; ++r) mk4[r] = *(const f32x4*)(mp + r*64);

    // QK^T: 3-term split over d=64
    f32x4 sc[4];
    const int c0 = ((0  + lg*16) ^ xork) >> 1;
    const int c1 = ((64 + lg*16) ^ xork) >> 1;
    #pragma unroll
    for (int nb = 0; nb < 4; ++nb) {
      const int krow = (nb*16 + lr)*64;
      short8 k0h = *(const short8*)&Ksh[cur][krow + c0];
      short8 k1h = *(const short8*)&Ksh[cur][krow + c1];
      short8 k0l = *(const short8*)&Ksl[cur][krow + c0];
      short8 k1l = *(const short8*)&Ksl[cur][krow + c1];
      f32x4 d = zero4;
      d = __builtin_amdgcn_mfma_f32_16x16x32_bf16(qfh[0], k0h, d, 0, 0, 0);
      d = __builtin_amdgcn_mfma_f32_16x16x32_bf16(qfh[1], k1h, d, 0, 0, 0);
      d = __builtin_amdgcn_mfma_f32_16x16x32_bf16(qfh[0], k0l, d, 0, 0, 0);
      d = __builtin_amdgcn_mfma_f32_16x16x32_bf16(qfh[1], k1l, d, 0, 0, 0);
      d = __builtin_amdgcn_mfma_f32_16x16x32_bf16(qfl[0], k0h, d, 0, 0, 0);
      d = __builtin_amdgcn_mfma_f32_16x16x32_bf16(qfl[1], k1h, d, 0, 0, 0);
      sc[nb] = d;
    }

    // online softmax
    float s[4][4], rmax[4];
    #pragma unroll
    for (int r = 0; r < 4; ++r) {
      float a0 = fmaf(sc[0][r], 0.125f, mk4[r][0]);
      float a1 = fmaf(sc[1][r], 0.125f, mk4[r][1]);
      float a2 = fmaf(sc[2][r], 0.125f, mk4[r][2]);
      float a3 = fmaf(sc[3][r], 0.125f, mk4[r][3]);
      s[0][r] = a0; s[1][r] = a1; s[2][r] = a2; s[3][r] = a3;
      rmax[r] = fmaxf(fmaxf(a0, a1), fmaxf(a2, a3));
    }
    #pragma unroll
    for (int off = 1; off < 16; off <<= 1) {
      #pragma unroll
      for (int r = 0; r < 4; ++r) rmax[r] = fmaxf(rmax[r], __shfl_xor(rmax[r], off, 16));
    }
    float corr[4];
    #pragma unroll
    for (int r = 0; r < 4; ++r) {
      float mn = fmaxf(m_run[r], rmax[r]);
      corr[r] = __expf(m_run[r] - mn);
      m_run[r] = mn;
      const int prow = 4*lg + r;
      const int pxor = (prow & 7) << 4;
      #pragma unroll
      for (int nb = 0; nb < 4; ++nb) {
        float pv = __expf(s[nb][r] - mn);
        P[w][prow*64 + (((((nb*16 + lr) << 1)) ^ pxor) >> 1)] = f2bf_fast(pv);
      }
    }
    #pragma unroll
    for (int d4 = 0; d4 < 4; ++d4)
      #pragma unroll
      for (int r = 0; r < 4; ++r) acc[d4][r] *= corr[r];
    #pragma unroll
    for (int r = 0; r < 4; ++r) acc_l[r] *= corr[r];

    // PV + row-sums (MFMA with B = ones)
    const int p0 = c0, p1 = c1;
    short8 pf0 = *(const short8*)&P[w][lr*64 + p0];
    short8 pf1 = *(const short8*)&P[w][lr*64 + p1];
    acc_l = __builtin_amdgcn_mfma_f32_16x16x32_bf16(pf0, ones8, acc_l, 0, 0, 0);
    acc_l = __builtin_amdgcn_mfma_f32_16x16x32_bf16(pf1, ones8, acc_l, 0, 0, 0);
    #pragma unroll
    for (int d4 = 0; d4 < 4; ++d4) {
      const int vrow = (d4*16 + lr)*64;
      short8 vf0 = *(const short8*)&Vss[cur][vrow + p0];
      short8 vf1 = *(const short8*)&Vss[cur][vrow + p1];
      acc[d4] = __builtin_amdgcn_mfma_f32_16x16x32_bf16(pf0, vf0, acc[d4], 0, 0, 0);
      acc[d4] = __builtin_amdgcn_mfma_f32_16x16x32_bf16(pf1, vf1, acc[d4], 0, 0, 0);
    }
  }
  #undef ATTN_STAGE

  float inv[4];
  #pragma unroll
  for (int r = 0; r < 4; ++r) inv[r] = 1.0f / acc_l[r];
  #pragma unroll
  for (int d4 = 0; d4 < 4; ++d4)
    #pragma unroll
    for (int r = 0; r < 4; ++r) {
      size_t o = ((size_t)(b*SS + q0 + 4*lg + r))*HH + hoff + d4*16 + lr;
      ao[o] = f2bf_fast(acc[d4][r] * inv[r]);
    }
}

// ---------------- launcher ----------------
extern "C" void kernel_launch(void* const* d_in, const int* in_sizes, int n_in,
                              void* d_out, int out_size, void* d_ws, size_t ws_size,
                              hipStream_t stream)
{
  const float* hs  = (const float*)d_in[0];
  const float* msk = (const float*)d_in[1];
  const float* qs  = (const float*)d_in[2];
  const float* qd  = (const float*)d_in[3];
  const float* ks  = (const float*)d_in[4];
  const float* kd  = (const float*)d_in[5];
  const float* vs  = (const float*)d_in[6];
  const float* vd  = (const float*)d_in[7];
  const float* os_ = (const float*)d_in[8];
  const float* od  = (const float*)d_in[9];
  float* out = (float*)d_out;

  const size_t NHS = (size_t)MM * HH;  // 4M elems
  const size_t NW  = (size_t)HH * HH;  // 1M elems
  unsigned short* p = (unsigned short*)d_ws;
  unsigned short* hsh = p; p += NHS;
  unsigned short* hsl = p; p += NHS;
  unsigned short* wqh = p; p += NW;
  unsigned short* wql = p; p += NW;
  unsigned short* wkh = p; p += NW;
  unsigned short* wkl = p; p += NW;
  unsigned short* wv  = p; p += NW;
  unsigned short* wo  = p; p += NW;
  unsigned short* qhB = p; p += NHS;
  unsigned short* qlB = p; p += NHS;
  unsigned short* khB = p; p += NHS;
  unsigned short* klB = p; p += NHS;
  unsigned short* vtB = p; p += NHS;
  unsigned short* aoB = p; p += NHS;
  float* pm = (float*)p;               // 2*32*2048*64 f32 = 33.5 MB
  // total ws: 76 MB + 33.5 MB

  k_split   <<<(int)(NHS/1024), 256, 0, stream>>>(hs, hsh, hsl, (int)(NHS/4));
  k_wprep   <<<(int)(4*N4SEG/256), 256, 0, stream>>>(qs, qd, ks, kd, vs, vd, os_, od,
                                                     wqh, wql, wkh, wkl, wv, wo);
  k_maskperm<<<8192, 256, 0, stream>>>(msk, pm);

  proj_fused<<<dim3(3*HH/128, MM/128), 256, 0, stream>>>(hsh, hsl, wqh, wql, wkh, wkl, wv,
                                                         qhB, qlB, khB, klB, vtB);

  attn_fwd<<<BB*NHH*(SS/128), 512, 0, stream>>>(qhB, qlB, khB, klB, vtB, pm, aoB);

  gemm_o<<<dim3(HH/128, MM/128), 256, 0, stream>>>(aoB, wo, out, MM, HH, HH);
}

// Round 7
// 332.222 us; speedup vs baseline: 1.8666x; 1.0646x over previous
//
#include <hip/hip_runtime.h>
#include <hip/hip_bf16.h>
#include <stdint.h>

#define BB 2
#define SS 2048
#define HH 1024
#define NHH 16
#define HDD 64
#define MM (BB*SS)   // 4096
#define N4SEG (HH*HH/4)   // 262144 = 2^18

typedef __attribute__((ext_vector_type(8))) short short8;
typedef __attribute__((ext_vector_type(4))) float f32x4;
typedef __attribute__((ext_vector_type(4))) unsigned short u16x4;
typedef __attribute__((ext_vector_type(4))) unsigned int u32x4;

__device__ __forceinline__ unsigned short f2bf(float x){
  unsigned u = __float_as_uint(x);
  u += 0x7fffu + ((u >> 16) & 1u);   // RNE; inputs are finite
  return (unsigned short)(u >> 16);
}
__device__ __forceinline__ float bf2f(unsigned short h){
  return __uint_as_float(((unsigned)h) << 16);
}
__device__ __forceinline__ unsigned short f2bf_fast(float x){
  __hip_bfloat16 hb = __float2bfloat16(x);
  return *reinterpret_cast<unsigned short*>(&hb);
}

// ---------------- conversion kernels ----------------
__global__ void k_split(const float* __restrict__ in, unsigned short* __restrict__ hi,
                        unsigned short* __restrict__ lo, int n4){
  int i = blockIdx.x * blockDim.x + threadIdx.x;
  if (i >= n4) return;
  f32x4 x = ((const f32x4*)in)[i];
  u16x4 h, l;
  #pragma unroll
  for (int j = 0; j < 4; ++j){
    unsigned short hb = f2bf(x[j]);
    h[j] = hb;
    l[j] = f2bf(x[j] - bf2f(hb));
  }
  ((u16x4*)hi)[i] = h;
  ((u16x4*)lo)[i] = l;
}

// all 4 weight preps in one launch: seg 0: q(split) 1: k(split) 2: v(plain) 3: o(plain)
__global__ void k_wprep(const float* __restrict__ qs, const float* __restrict__ qd,
                        const float* __restrict__ ks, const float* __restrict__ kd,
                        const float* __restrict__ vs, const float* __restrict__ vd,
                        const float* __restrict__ os_, const float* __restrict__ od,
                        unsigned short* __restrict__ wqh, unsigned short* __restrict__ wql,
                        unsigned short* __restrict__ wkh, unsigned short* __restrict__ wkl,
                        unsigned short* __restrict__ wv,  unsigned short* __restrict__ wo){
  int i = blockIdx.x * blockDim.x + threadIdx.x;
  int seg = i >> 18;
  int j = i & (N4SEG - 1);
  const float *pa, *pb; unsigned short *ph, *pl = nullptr;
  if      (seg == 0){ pa = qs; pb = qd; ph = wqh; pl = wql; }
  else if (seg == 1){ pa = ks; pb = kd; ph = wkh; pl = wkl; }
  else if (seg == 2){ pa = vs; pb = vd; ph = wv; }
  else              { pa = os_; pb = od; ph = wo; }
  f32x4 x = ((const f32x4*)pa)[j] + ((const f32x4*)pb)[j];
  u16x4 h, l;
  #pragma unroll
  for (int c = 0; c < 4; ++c){
    unsigned short hb = f2bf(x[c]);
    h[c] = hb;
    l[c] = f2bf(x[c] - bf2f(hb));
  }
  ((u16x4*)ph)[j] = h;
  if (pl) ((u16x4*)pl)[j] = l;
}

// ---------------- fused QKV projection ----------------
__global__ __launch_bounds__(256, 2)
void proj_fused(const unsigned short* __restrict__ hsh, const unsigned short* __restrict__ hsl,
                const unsigned short* __restrict__ wqh, const unsigned short* __restrict__ wql,
                const unsigned short* __restrict__ wkh, const unsigned short* __restrict__ wkl,
                const unsigned short* __restrict__ wv,
                unsigned short* __restrict__ qhB, unsigned short* __restrict__ qlB,
                unsigned short* __restrict__ khB, unsigned short* __restrict__ klB,
                unsigned short* __restrict__ vtB)
{
  __shared__ unsigned short Ash[128*32], Asl[128*32], Bsh[128*32], Bsl[128*32];
  const int tid = threadIdx.x;
  const int nb0 = blockIdx.x * 128;        // 0..3071
  const int mb0 = blockIdx.y * 128;
  const int kind = nb0 >> 10;              // 0=q 1=k 2=v
  const int ncol0 = nb0 & 1023;
  const int w  = tid >> 6, lane = tid & 63;
  const int wr = w >> 1,  wc = w & 1;
  const int lg = lane >> 4, lr = lane & 15;

  const unsigned short* Bh = (kind == 0 ? wqh : (kind == 1 ? wkh : wv)) + (size_t)ncol0 * HH;
  const unsigned short* Bl = (kind == 0 ? wql : wkl) + (size_t)ncol0 * HH;  // unused for v
  const unsigned short* Ahb = hsh + (size_t)mb0 * HH;
  const unsigned short* Alb = hsl + (size_t)mb0 * HH;

  f32x4 zero4 = {0.f, 0.f, 0.f, 0.f};
  f32x4 acc[4][4];
  #pragma unroll
  for (int mi = 0; mi < 4; ++mi)
    #pragma unroll
    for (int ni = 0; ni < 4; ++ni) acc[mi][ni] = zero4;

  for (int kb = 0; kb < HH; kb += 32) {
    __syncthreads();
    #pragma unroll
    for (int i = 0; i < 2; ++i){
      int c = i*256 + tid;
      int row = c >> 2, off = (c & 3) << 3;
      size_t go = (size_t)row * HH + kb + off;
      __builtin_amdgcn_global_load_lds(
          (const __attribute__((address_space(1))) void*)(Ahb + go),
          (__attribute__((address_space(3))) void*)(&Ash[c*8]), 16, 0, 0);
      __builtin_amdgcn_global_load_lds(
          (const __attribute__((address_space(1))) void*)(Alb + go),
          (__attribute__((address_space(3))) void*)(&Asl[c*8]), 16, 0, 0);
      __builtin_amdgcn_global_load_lds(
          (const __attribute__((address_space(1))) void*)(Bh + go),
          (__attribute__((address_space(3))) void*)(&Bsh[c*8]), 16, 0, 0);
      if (kind < 2)
        __builtin_amdgcn_global_load_lds(
            (const __attribute__((address_space(1))) void*)(Bl + go),
            (__attribute__((address_space(3))) void*)(&Bsl[c*8]), 16, 0, 0);
    }
    __syncthreads();
    short8 ah4[4], al4[4], bh4[4], bl4[4];
    #pragma unroll
    for (int mi = 0; mi < 4; ++mi){
      int ro = (wr*64 + mi*16 + lr)*32 + lg*8;
      ah4[mi] = *(const short8*)&Ash[ro];
      al4[mi] = *(const short8*)&Asl[ro];
    }
    #pragma unroll
    for (int ni = 0; ni < 4; ++ni){
      int ro = (wc*64 + ni*16 + lr)*32 + lg*8;
      bh4[ni] = *(const short8*)&Bsh[ro];
    }
    if (kind < 2) {
      #pragma unroll
      for (int ni = 0; ni < 4; ++ni){
        int ro = (wc*64 + ni*16 + lr)*32 + lg*8;
        bl4[ni] = *(const short8*)&Bsl[ro];
      }
      #pragma unroll
      for (int mi = 0; mi < 4; ++mi)
        #pragma unroll
        for (int ni = 0; ni < 4; ++ni){
          acc[mi][ni] = __builtin_amdgcn_mfma_f32_16x16x32_bf16(ah4[mi], bh4[ni], acc[mi][ni], 0, 0, 0);
          acc[mi][ni] = __builtin_amdgcn_mfma_f32_16x16x32_bf16(al4[mi], bh4[ni], acc[mi][ni], 0, 0, 0);
          acc[mi][ni] = __builtin_amdgcn_mfma_f32_16x16x32_bf16(ah4[mi], bl4[ni], acc[mi][ni], 0, 0, 0);
        }
    } else {
      #pragma unroll
      for (int mi = 0; mi < 4; ++mi)
        #pragma unroll
        for (int ni = 0; ni < 4; ++ni)
          acc[mi][ni] = __builtin_amdgcn_mfma_f32_16x16x32_bf16(ah4[mi], bh4[ni], acc[mi][ni], 0, 0, 0);
    }
  }

  if (kind == 2) {
    #pragma unroll
    for (int mi = 0; mi < 4; ++mi){
      #pragma unroll
      for (int ni = 0; ni < 4; ++ni){
        int nv = ncol0 + wc*64 + ni*16 + lr;
        int m0 = mb0 + wr*64 + mi*16 + 4*lg;
        int b = m0 >> 11, s0 = m0 & 2047;
        u16x4 pk;
        #pragma unroll
        for (int r = 0; r < 4; ++r) pk[r] = f2bf_fast(acc[mi][ni][r]);
        *(u16x4*)&vtB[((size_t)(b*HH + nv))*SS + s0] = pk;
      }
    }
  } else {
    unsigned short* Ch = (kind == 0) ? qhB : khB;
    unsigned short* Cl = (kind == 0) ? qlB : klB;
    #pragma unroll
    for (int mi = 0; mi < 4; ++mi){
      #pragma unroll
      for (int ni = 0; ni < 4; ++ni){
        int n  = ncol0 + wc*64 + ni*16 + lr;
        int m0 = mb0 + wr*64 + mi*16 + 4*lg;
        #pragma unroll
        for (int r = 0; r < 4; ++r){
          float x = acc[mi][ni][r];
          unsigned short hb = f2bf(x);
          unsigned short lb = f2bf(x - bf2f(hb));
          size_t o = (size_t)(m0 + r)*HH + n;
          Ch[o] = hb;
          Cl[o] = lb;
        }
      }
    }
  }
}

// ---------------- O-projection GEMM ----------------
__global__ __launch_bounds__(256, 2)
void gemm_o(const unsigned short* __restrict__ A, const unsigned short* __restrict__ Bm,
            float* __restrict__ C, int M, int N, int K)
{
  __shared__ unsigned short As[128*32];
  __shared__ unsigned short Bs[128*32];
  const int tid = threadIdx.x;
  const int mb0 = blockIdx.y * 128, nb0 = blockIdx.x * 128;
  const int w  = tid >> 6, lane = tid & 63;
  const int wr = w >> 1,  wc = w & 1;
  const int lg = lane >> 4, lr = lane & 15;

  f32x4 zero4 = {0.f, 0.f, 0.f, 0.f};
  f32x4 acc[4][4];
  #pragma unroll
  for (int mi = 0; mi < 4; ++mi)
    #pragma unroll
    for (int ni = 0; ni < 4; ++ni) acc[mi][ni] = zero4;

  const unsigned short* Abase = A  + (size_t)mb0 * K;
  const unsigned short* Bbase = Bm + (size_t)nb0 * K;

  for (int kb = 0; kb < K; kb += 32) {
    __syncthreads();
    #pragma unroll
    for (int i = 0; i < 2; ++i){
      int c = i*256 + tid;
      int row = c >> 2, off = (c & 3) << 3;
      size_t go = (size_t)row * K + kb + off;
      __builtin_amdgcn_global_load_lds(
          (const __attribute__((address_space(1))) void*)(Abase + go),
          (__attribute__((address_space(3))) void*)(&As[c*8]), 16, 0, 0);
      __builtin_amdgcn_global_load_lds(
          (const __attribute__((address_space(1))) void*)(Bbase + go),
          (__attribute__((address_space(3))) void*)(&Bs[c*8]), 16, 0, 0);
    }
    __syncthreads();
    short8 af[4], bfr[4];
    #pragma unroll
    for (int mi = 0; mi < 4; ++mi) af[mi]  = *(const short8*)&As[(wr*64 + mi*16 + lr)*32 + lg*8];
    #pragma unroll
    for (int ni = 0; ni < 4; ++ni) bfr[ni] = *(const short8*)&Bs[(wc*64 + ni*16 + lr)*32 + lg*8];
    #pragma unroll
    for (int mi = 0; mi < 4; ++mi)
      #pragma unroll
      for (int ni = 0; ni < 4; ++ni)
        acc[mi][ni] = __builtin_amdgcn_mfma_f32_16x16x32_bf16(af[mi], bfr[ni], acc[mi][ni], 0, 0, 0);
  }

  #pragma unroll
  for (int mi = 0; mi < 4; ++mi){
    #pragma unroll
    for (int ni = 0; ni < 4; ++ni){
      int n  = nb0 + wc*64 + ni*16 + lr;
      int m0 = mb0 + wr*64 + mi*16 + 4*lg;
      #pragma unroll
      for (int r = 0; r < 4; ++r) C[(size_t)(m0 + r)*N + n] = acc[mi][ni][r];
    }
  }
}

// ---------------- flash attention (v5: swapped QK^T, in-register P, NO defer-max,
// NO inline-asm cvt_pk — bisecting v4's failure) ----------------
__global__ __launch_bounds__(512, 4)
void attn_fwd(const unsigned short* __restrict__ qh, const unsigned short* __restrict__ ql,
              const unsigned short* __restrict__ kh, const unsigned short* __restrict__ kl,
              const unsigned short* __restrict__ vt, const float* __restrict__ mask,
              unsigned short* __restrict__ ao)
{
  __shared__ unsigned short Ksh[2][64*64];
  __shared__ unsigned short Ksl[2][64*64];
  __shared__ unsigned short Vss[2][64*64];

  const int tid = threadIdx.x;
  const int w = tid >> 6, lane = tid & 63;
  const int lg = lane >> 4, lr = lane & 15;
  const int xork = (lr & 7) << 4;

  // XCD-aware bijective remap (512 % 8 == 0)
  const int bid = (blockIdx.x & 7) * 64 + (blockIdx.x >> 3);
  const int qb = bid & 15, h = (bid >> 4) & 15, b = bid >> 8;
  const int q0 = qb*128 + w*16;
  const int hoff = h*64;

  const int srow = tid >> 3;
  const int sgx  = (tid & 7) ^ (srow & 7);

  // bpermute byte-addresses (loop-invariant)
  const int aLO = ((lg & 1)*32 + lr) * 4;     // source lane 32*(lg&1)+lr (owns q=lr)
  const int aHI = aLO + 64;                   // source lane +16
  int addr_c[4];
  #pragma unroll
  for (int r = 0; r < 4; ++r) addr_c[r] = (lg*20 + r) * 4;  // lane 16*lg + (4*lg+r)

  short8 qfh[2], qfl[2];
  {
    size_t qoff = ((size_t)(b*SS + q0 + lr))*HH + hoff + lg*8;
    qfh[0] = *(const short8*)(qh + qoff);
    qfl[0] = *(const short8*)(ql + qoff);
    qfh[1] = *(const short8*)(qh + qoff + 32);
    qfl[1] = *(const short8*)(ql + qoff + 32);
  }
  short8 ones8;
  #pragma unroll
  for (int j = 0; j < 8; ++j) ones8[j] = (short)0x3F80;   // bf16 1.0

  float m_run = -1e30f;                       // per lane: running max for q = lr
  f32x4 zero4 = {0.f, 0.f, 0.f, 0.f};
  f32x4 acc[4], acc_l = zero4;
  #pragma unroll
  for (int d4 = 0; d4 < 4; ++d4) acc[d4] = zero4;

  // mask row for q = q0 + lr; per-step dwordx4 at col kv + nb*16 + 4*lg
  const float* mrow = mask + ((size_t)(b*SS + q0 + lr))*SS + 4*lg;

  #define ATTN_STAGE(buf, kvb) do {                                              \
    size_t kro = ((size_t)(b*SS + (kvb) + srow))*HH + hoff + sgx*8;              \
    size_t vro = ((size_t)(b*HH + hoff + srow))*SS + (kvb) + sgx*8;              \
    __builtin_amdgcn_global_load_lds(                                            \
        (const __attribute__((address_space(1))) void*)(kh + kro),               \
        (__attribute__((address_space(3))) void*)(&Ksh[buf][tid*8]), 16, 0, 0);  \
    __builtin_amdgcn_global_load_lds(                                            \
        (const __attribute__((address_space(1))) void*)(kl + kro),               \
        (__attribute__((address_space(3))) void*)(&Ksl[buf][tid*8]), 16, 0, 0);  \
    __builtin_amdgcn_global_load_lds(                                            \
        (const __attribute__((address_space(1))) void*)(vt + vro),               \
        (__attribute__((address_space(3))) void*)(&Vss[buf][tid*8]), 16, 0, 0);  \
  } while (0)

  ATTN_STAGE(0, 0);

  for (int t = 0; t < SS/64; ++t) {
    const int kv = t*64;
    const int cur = t & 1;
    __syncthreads();
    if (t + 1 < SS/64) ATTN_STAGE(cur ^ 1, kv + 64);

    // mask: 4 coalesced dwordx4 from the original layout (lane-local k-slice)
    f32x4 mk[4];
    #pragma unroll
    for (int nb = 0; nb < 4; ++nb) mk[nb] = *(const f32x4*)(mrow + kv + nb*16);

    // QK^T swapped: sc[nb] = C[k-block nb][q=lr]; reg r -> k = kv + 16nb + 4lg + r
    const int c0 = ((0  + lg*16) ^ xork) >> 1;
    const int c1 = ((64 + lg*16) ^ xork) >> 1;
    f32x4 sc[4];
    #pragma unroll
    for (int nb = 0; nb < 4; ++nb) {
      const int krow = (nb*16 + lr)*64;
      short8 k0h = *(const short8*)&Ksh[cur][krow + c0];
      short8 k1h = *(const short8*)&Ksh[cur][krow + c1];
      short8 k0l = *(const short8*)&Ksl[cur][krow + c0];
      short8 k1l = *(const short8*)&Ksl[cur][krow + c1];
      f32x4 d = zero4;
      d = __builtin_amdgcn_mfma_f32_16x16x32_bf16(k0h, qfh[0], d, 0, 0, 0);
      d = __builtin_amdgcn_mfma_f32_16x16x32_bf16(k1h, qfh[1], d, 0, 0, 0);
      d = __builtin_amdgcn_mfma_f32_16x16x32_bf16(k0l, qfh[0], d, 0, 0, 0);
      d = __builtin_amdgcn_mfma_f32_16x16x32_bf16(k1l, qfh[1], d, 0, 0, 0);
      d = __builtin_amdgcn_mfma_f32_16x16x32_bf16(k0h, qfl[0], d, 0, 0, 0);
      d = __builtin_amdgcn_mfma_f32_16x16x32_bf16(k1h, qfl[1], d, 0, 0, 0);
      sc[nb] = d;
    }

    // lane-local scores + row max (16 values for q=lr; combine across lg groups)
    float s[4][4];
    float rmax = -1e30f;
    #pragma unroll
    for (int nb = 0; nb < 4; ++nb)
      #pragma unroll
      for (int r = 0; r < 4; ++r) {
        float v = fmaf(sc[nb][r], 0.125f, mk[nb][r]);
        s[nb][r] = v;
        rmax = fmaxf(rmax, v);
      }
    rmax = fmaxf(rmax, __shfl_xor(rmax, 16));
    rmax = fmaxf(rmax, __shfl_xor(rmax, 32));

    // always-rescale (v3 semantics; defer-max removed for bisection)
    float mn = fmaxf(m_run, rmax);
    float corr = __expf(m_run - mn);
    m_run = mn;
    #pragma unroll
    for (int r = 0; r < 4; ++r) {
      float ca = __int_as_float(
          __builtin_amdgcn_ds_bpermute(addr_c[r], __float_as_int(corr)));
      acc_l[r] *= ca;
      #pragma unroll
      for (int d4 = 0; d4 < 4; ++d4) acc[d4][r] *= ca;
    }

    // P = exp(s - m_run) packed to bf16 pairs via verified manual RNE (no asm)
    unsigned pw[4][2];
    #pragma unroll
    for (int nb = 0; nb < 4; ++nb) {
      float e0 = __expf(s[nb][0] - m_run);
      float e1 = __expf(s[nb][1] - m_run);
      float e2 = __expf(s[nb][2] - m_run);
      float e3 = __expf(s[nb][3] - m_run);
      pw[nb][0] = (unsigned)f2bf(e0) | ((unsigned)f2bf(e1) << 16);
      pw[nb][1] = (unsigned)f2bf(e2) | ((unsigned)f2bf(e3) << 16);
    }

    // gather PV A-fragments: lane (lg,lr) needs P[q=lr][k = 8lg..8lg+7] (pf0)
    // and [32+8lg..] (pf1), from lanes 32(lg&1)+{0,16}+lr, block select lg>>1.
    const int B0 = lg >> 1;
    u32x4 f0, f1;
    {
      unsigned g0 = __builtin_amdgcn_ds_bpermute(aLO, (int)pw[0][0]);
      unsigned g1 = __builtin_amdgcn_ds_bpermute(aLO, (int)pw[0][1]);
      unsigned g2 = __builtin_amdgcn_ds_bpermute(aLO, (int)pw[1][0]);
      unsigned g3 = __builtin_amdgcn_ds_bpermute(aLO, (int)pw[1][1]);
      unsigned g4 = __builtin_amdgcn_ds_bpermute(aHI, (int)pw[0][0]);
      unsigned g5 = __builtin_amdgcn_ds_bpermute(aHI, (int)pw[0][1]);
      unsigned g6 = __builtin_amdgcn_ds_bpermute(aHI, (int)pw[1][0]);
      unsigned g7 = __builtin_amdgcn_ds_bpermute(aHI, (int)pw[1][1]);
      f0[0] = B0 ? g2 : g0;
      f0[1] = B0 ? g3 : g1;
      f0[2] = B0 ? g6 : g4;
      f0[3] = B0 ? g7 : g5;
    }
    {
      unsigned g0 = __builtin_amdgcn_ds_bpermute(aLO, (int)pw[2][0]);
      unsigned g1 = __builtin_amdgcn_ds_bpermute(aLO, (int)pw[2][1]);
      unsigned g2 = __builtin_amdgcn_ds_bpermute(aLO, (int)pw[3][0]);
      unsigned g3 = __builtin_amdgcn_ds_bpermute(aLO, (int)pw[3][1]);
      unsigned g4 = __builtin_amdgcn_ds_bpermute(aHI, (int)pw[2][0]);
      unsigned g5 = __builtin_amdgcn_ds_bpermute(aHI, (int)pw[2][1]);
      unsigned g6 = __builtin_amdgcn_ds_bpermute(aHI, (int)pw[3][0]);
      unsigned g7 = __builtin_amdgcn_ds_bpermute(aHI, (int)pw[3][1]);
      f1[0] = B0 ? g2 : g0;
      f1[1] = B0 ? g3 : g1;
      f1[2] = B0 ? g6 : g4;
      f1[3] = B0 ? g7 : g5;
    }
    short8 pf0 = *reinterpret_cast<short8*>(&f0);
    short8 pf1 = *reinterpret_cast<short8*>(&f1);

    // row sums via MFMA-ones (acc_l row q = 4lg+r, matches acc layout)
    acc_l = __builtin_amdgcn_mfma_f32_16x16x32_bf16(pf0, ones8, acc_l, 0, 0, 0);
    acc_l = __builtin_amdgcn_mfma_f32_16x16x32_bf16(pf1, ones8, acc_l, 0, 0, 0);

    // PV
    #pragma unroll
    for (int d4 = 0; d4 < 4; ++d4) {
      const int vrow = (d4*16 + lr)*64;
      short8 vf0 = *(const short8*)&Vss[cur][vrow + c0];
      short8 vf1 = *(const short8*)&Vss[cur][vrow + c1];
      acc[d4] = __builtin_amdgcn_mfma_f32_16x16x32_bf16(pf0, vf0, acc[d4], 0, 0, 0);
      acc[d4] = __builtin_amdgcn_mfma_f32_16x16x32_bf16(pf1, vf1, acc[d4], 0, 0, 0);
    }
  }
  #undef ATTN_STAGE

  float inv[4];
  #pragma unroll
  for (int r = 0; r < 4; ++r) inv[r] = 1.0f / acc_l[r];
  #pragma unroll
  for (int d4 = 0; d4 < 4; ++d4)
    #pragma unroll
    for (int r = 0; r < 4; ++r) {
      size_t o = ((size_t)(b*SS + q0 + 4*lg + r))*HH + hoff + d4*16 + lr;
      ao[o] = f2bf_fast(acc[d4][r] * inv[r]);
    }
}

// ---------------- launcher ----------------
extern "C" void kernel_launch(void* const* d_in, const int* in_sizes, int n_in,
                              void* d_out, int out_size, void* d_ws, size_t ws_size,
                              hipStream_t stream)
{
  const float* hs  = (const float*)d_in[0];
  const float* msk = (const float*)d_in[1];
  const float* qs  = (const float*)d_in[2];
  const float* qd  = (const float*)d_in[3];
  const float* ks  = (const float*)d_in[4];
  const float* kd  = (const float*)d_in[5];
  const float* vs  = (const float*)d_in[6];
  const float* vd  = (const float*)d_in[7];
  const float* os_ = (const float*)d_in[8];
  const float* od  = (const float*)d_in[9];
  float* out = (float*)d_out;

  const size_t NHS = (size_t)MM * HH;  // 4M elems
  const size_t NW  = (size_t)HH * HH;  // 1M elems
  unsigned short* p = (unsigned short*)d_ws;
  unsigned short* hsh = p; p += NHS;
  unsigned short* hsl = p; p += NHS;
  unsigned short* wqh = p; p += NW;
  unsigned short* wql = p; p += NW;
  unsigned short* wkh = p; p += NW;
  unsigned short* wkl = p; p += NW;
  unsigned short* wv  = p; p += NW;
  unsigned short* wo  = p; p += NW;
  unsigned short* qhB = p; p += NHS;
  unsigned short* qlB = p; p += NHS;
  unsigned short* khB = p; p += NHS;
  unsigned short* klB = p; p += NHS;
  unsigned short* vtB = p; p += NHS;
  unsigned short* aoB = p; p += NHS;
  // total: 38M elems * 2B = 76 MB of d_ws

  k_split<<<(int)(NHS/1024), 256, 0, stream>>>(hs, hsh, hsl, (int)(NHS/4));
  k_wprep<<<(int)(4*N4SEG/256), 256, 0, stream>>>(qs, qd, ks, kd, vs, vd, os_, od,
                                                  wqh, wql, wkh, wkl, wv, wo);

  proj_fused<<<dim3(3*HH/128, MM/128), 256, 0, stream>>>(hsh, hsl, wqh, wql, wkh, wkl, wv,
                                                         qhB, qlB, khB, klB, vtB);

  attn_fwd<<<BB*NHH*(SS/128), 512, 0, stream>>>(qhB, qlB, khB, klB, vtB, msk, aoB);

  gemm_o<<<dim3(HH/128, MM/128), 256, 0, stream>>>(aoB, wo, out, MM, HH, HH);
}